// Round 7
// baseline (126.202 us; speedup 1.0000x reference)
//
#include <hip/hip_runtime.h>
#include <math.h>

#define T_SEQ 2048
#define D_MODEL 1024
#define NH 16
#define HD 64
#define RMS_EPS 1.1920928955078125e-07f

typedef unsigned short ushort_t;
typedef __attribute__((ext_vector_type(8))) short short8;
typedef __attribute__((ext_vector_type(8))) unsigned short ushort8;
typedef __attribute__((ext_vector_type(4))) float f32x4;

static __device__ __forceinline__ unsigned short f2bf(float f) {
    union { float f; unsigned u; } v; v.f = f;
    unsigned r = v.u + 0x7fff + ((v.u >> 16) & 1);   // RNE
    return (unsigned short)(r >> 16);
}
static __device__ __forceinline__ float bf2f(unsigned short b) {
    union { unsigned u; float f; } v; v.u = ((unsigned)b) << 16;
    return v.f;
}
static __device__ __forceinline__ unsigned cvt_pk_bf16(float lo, float hi) {
    unsigned r;
    asm("v_cvt_pk_bf16_f32 %0, %1, %2" : "=v"(r) : "v"(lo), "v"(hi));
    return r;
}
static __device__ __forceinline__ void gl_lds16(const ushort_t* g, ushort_t* l) {
    __builtin_amdgcn_global_load_lds(
        (const __attribute__((address_space(1))) unsigned int*)g,
        (__attribute__((address_space(3))) unsigned int*)l, 16, 0, 0);
}

// ---------------------------------------------------------------------------
// Cast f32 -> bf16: x (2M elements, segs 0-1) and the 4 weights (1M each).
// ---------------------------------------------------------------------------
__global__ __launch_bounds__(256) void cast_to_bf16(
    const float* __restrict__ x, const float* __restrict__ wq,
    const float* __restrict__ wk, const float* __restrict__ wv,
    const float* __restrict__ wo,
    ushort_t* __restrict__ xb, ushort_t* __restrict__ wqb,
    ushort_t* __restrict__ wkb, ushort_t* __restrict__ wvb,
    ushort_t* __restrict__ wob) {
    const int seg = blockIdx.y;
    const float* src; ushort_t* dst; size_t base = 0;
    if (seg == 0)      { src = x;  dst = xb; }
    else if (seg == 1) { src = x;  dst = xb; base = 1u << 20; }
    else if (seg == 2) { src = wq; dst = wqb; }
    else if (seg == 3) { src = wk; dst = wkb; }
    else if (seg == 4) { src = wv; dst = wvb; }
    else               { src = wo; dst = wob; }
    const size_t i = base + ((size_t)blockIdx.x * 256 + threadIdx.x) * 8;
    float4 a = *(const float4*)&src[i];
    float4 b = *(const float4*)&src[i + 4];
    ushort8 o;
    o[0] = f2bf(a.x); o[1] = f2bf(a.y); o[2] = f2bf(a.z); o[3] = f2bf(a.w);
    o[4] = f2bf(b.x); o[5] = f2bf(b.y); o[6] = f2bf(b.z); o[7] = f2bf(b.w);
    *(ushort8*)&dst[i] = o;
}

// ---------------------------------------------------------------------------
// bf16 MFMA GEMM (unchanged from r4): C[M,N] = A[M,K] @ B[N,K]^T.
// ---------------------------------------------------------------------------
template<bool BF16OUT>
__global__ __launch_bounds__(256) void gemm_bf16_nt(
    const ushort_t* __restrict__ A,
    const ushort_t* __restrict__ B0, const ushort_t* __restrict__ B1,
    const ushort_t* __restrict__ B2,
    void* __restrict__ C0, void* __restrict__ C1, void* __restrict__ C2,
    int M, int N, int K) {
    __shared__ ushort_t As[128 * 64];
    __shared__ ushort_t Bs[128 * 64];

    const int z = blockIdx.z;
    const ushort_t* B = (z == 0) ? B0 : (z == 1) ? B1 : B2;
    void* Cv          = (z == 0) ? C0 : (z == 1) ? C1 : C2;

    const int tid = threadIdx.x;
    const int w = tid >> 6;
    const int l = tid & 63;
    const int wr = w >> 1, wc = w & 1;
    const int l16 = l & 15, g4 = l >> 4;
    const int row0 = blockIdx.y * 128;
    const int col0 = blockIdx.x * 128;

    const int srow = tid >> 3;
    const int scol = (tid & 7) * 8;
    const ushort_t* ga = A + (size_t)(row0 + srow) * K + scol;
    const ushort_t* gb = B + (size_t)(col0 + srow) * K + scol;
    ushort_t* lA = &As[w * 512];
    ushort_t* lB = &Bs[w * 512];

    f32x4 acc[4][4];
#pragma unroll
    for (int m = 0; m < 4; ++m)
#pragma unroll
        for (int n = 0; n < 4; ++n)
            acc[m][n] = (f32x4){0.0f, 0.0f, 0.0f, 0.0f};

    for (int k0 = 0; k0 < K; k0 += 64) {
        __syncthreads();
#pragma unroll
        for (int i = 0; i < 4; ++i) {
            gl_lds16(ga + (size_t)i * 32 * K + k0, lA + i * 2048);
            gl_lds16(gb + (size_t)i * 32 * K + k0, lB + i * 2048);
        }
        __syncthreads();
#pragma unroll
        for (int kk = 0; kk < 2; ++kk) {
            short8 af[4], bfr[4];
#pragma unroll
            for (int m = 0; m < 4; ++m)
                af[m] = *(const short8*)&As[(wr * 64 + m * 16 + l16) * 64 + kk * 32 + g4 * 8];
#pragma unroll
            for (int n = 0; n < 4; ++n)
                bfr[n] = *(const short8*)&Bs[(wc * 64 + n * 16 + l16) * 64 + kk * 32 + g4 * 8];
#pragma unroll
            for (int m = 0; m < 4; ++m)
#pragma unroll
                for (int n = 0; n < 4; ++n)
                    acc[m][n] = __builtin_amdgcn_mfma_f32_16x16x32_bf16(af[m], bfr[n], acc[m][n], 0, 0, 0);
        }
    }

#pragma unroll
    for (int m = 0; m < 4; ++m) {
        const int grow = row0 + wr * 64 + m * 16 + g4 * 4;
#pragma unroll
        for (int n = 0; n < 4; ++n) {
            const int gcol = col0 + wc * 64 + n * 16 + l16;
#pragma unroll
            for (int r = 0; r < 4; ++r) {
                if (BF16OUT)
                    ((ushort_t*)Cv)[(size_t)(grow + r) * N + gcol] = f2bf(acc[m][n][r]);
                else
                    ((float*)Cv)[(size_t)(grow + r) * N + gcol] = acc[m][n][r];
            }
        }
    }
}

// ---------------------------------------------------------------------------
// In-place on bf16 q,k,v: v-blend, rmsnorm, rope (unchanged from r4).
// ---------------------------------------------------------------------------
__global__ __launch_bounds__(256) void norm_rope(ushort_t* __restrict__ qb,
                                                 ushort_t* __restrict__ kb,
                                                 ushort_t* __restrict__ vb,
                                                 const float* __restrict__ vi,
                                                 const float* __restrict__ lamb) {
    const int w = threadIdx.x >> 6;
    const int lane = threadIdx.x & 63;
    const int t = blockIdx.x;
    const int h = blockIdx.y * 4 + w;
    const size_t idx = (size_t)t * D_MODEL + h * HD + lane;

    const float lam = lamb[0];
    float qv = bf2f(qb[idx]);
    float kv = bf2f(kb[idx]);
    float vv = (1.0f - lam) * bf2f(vb[idx]) + lam * vi[idx];
    vb[idx] = f2bf(vv);

    float sq = qv * qv;
    float sk = kv * kv;
#pragma unroll
    for (int m = 1; m <= 32; m <<= 1) {
        sq += __shfl_xor(sq, m, 64);
        sk += __shfl_xor(sk, m, 64);
    }
    const float rq = rsqrtf(sq * (1.0f / 64.0f) + RMS_EPS);
    const float rk = rsqrtf(sk * (1.0f / 64.0f) + RMS_EPS);
    float qn = qv * rq;
    float kn = kv * rk;

    const int i = lane & 31;
    const float inv = exp2f(-0.4152410118609203f * (float)i);
    const float ang = (float)t * inv;
    float c, s;
    sincosf(ang, &s, &c);
    float qp = __shfl_xor(qn, 32, 64);
    float kp = __shfl_xor(kn, 32, 64);
    float qo, ko;
    if (lane < 32) {
        qo = qn * c + qp * s;
        ko = kn * c + kp * s;
    } else {
        qo = qn * c - qp * s;
        ko = kn * c - kp * s;
    }
    qb[idx] = f2bf(qo);
    kb[idx] = f2bf(ko);
}

// ---------------------------------------------------------------------------
// Flash attention v3: split-K over key tiles for qt>=16 (two half blocks
// writing f32 partials; combiner merges). Swapped QK^T, reg prefetch,
// double-buffered V in LDS, cvt_pk_bf16 P-stores.
//
// Grid = 768: b in [0,512): split halves, qt = 31-(b>>5), h=(b&31)>>1,
// half=b&1. b in [512,768): full units qt = 15-((b-512)>>4), h=(b-512)&15.
// ---------------------------------------------------------------------------
__global__ __launch_bounds__(256) void attn_mfma(const ushort_t* __restrict__ qb,
                                                 const ushort_t* __restrict__ kb,
                                                 const ushort_t* __restrict__ vb,
                                                 const float* __restrict__ sink,
                                                 ushort_t* __restrict__ yb,
                                                 float* __restrict__ part_acc,
                                                 float* __restrict__ part_ml) {
    const int b = blockIdx.x;
    int h, qt, kt0, kt1, mode;   // mode 0 = full->y, 1/2 = partial half 0/1
    if (b < 512) {
        qt = 31 - (b >> 5);
        const int rem = b & 31;
        h = rem >> 1;
        const int half = rem & 1;
        const int mid = (qt + 1) >> 1;
        kt0 = half ? mid : 0;
        kt1 = half ? (qt + 1) : mid;
        mode = 1 + half;
    } else {
        const int rem = b - 512;
        qt = 15 - (rem >> 4);
        h = rem & 15;
        kt0 = 0; kt1 = qt + 1; mode = 0;
    }

    __shared__ ushort_t Vt[2][64][72];      // V transposed, double-buffered
    __shared__ ushort_t Pl[4][16][72];      // per-wave P (wave-local)

    const int tid  = threadIdx.x;
    const int w    = tid >> 6;
    const int lane = tid & 63;
    const int l16  = lane & 15;
    const int g4   = lane >> 4;

    // Q B-frags (persist): B[k=d][col=q=l16]
    const size_t qoff = (size_t)(qt * 64 + w * 16 + l16) * D_MODEL + h * HD;
    const short8 q0 = *(const short8*)&qb[qoff + 8 * g4];
    const short8 q1 = *(const short8*)&qb[qoff + 32 + 8 * g4];

    // current K A-frags + V staging regs (tile kt0)
    short8 ka0[4], ka1[4];
    ushort8 va0, va1;
#pragma unroll
    for (int s = 0; s < 4; ++s) {
        const size_t koff = (size_t)(kt0 * 64 + s * 16 + l16) * D_MODEL + h * HD;
        ka0[s] = *(const short8*)&kb[koff + 8 * g4];
        ka1[s] = *(const short8*)&kb[koff + 32 + 8 * g4];
    }
    {
        const size_t voff = (size_t)(kt0 * 64 + lane) * D_MODEL + h * HD + w * 16;
        va0 = *(const ushort8*)&vb[voff];
        va1 = *(const ushort8*)&vb[voff + 8];
    }

    float m = -INFINITY, lsum = 0.0f;
    f32x4 acc[4];
#pragma unroll
    for (int d = 0; d < 4; ++d) acc[d] = (f32x4){0.0f, 0.0f, 0.0f, 0.0f};

    for (int kt = kt0; kt < kt1; ++kt) {
        const int cur = kt & 1;

        // stage current V regs -> Vt[cur]
#pragma unroll
        for (int j = 0; j < 8; ++j) {
            Vt[cur][w * 16 + j][lane]     = va0[j];
            Vt[cur][w * 16 + 8 + j][lane] = va1[j];
        }

        // prefetch next tile K/V into regs
        short8 kn0[4], kn1[4];
        ushort8 vn0, vn1;
        if (kt + 1 < kt1) {
#pragma unroll
            for (int s = 0; s < 4; ++s) {
                const size_t koff = (size_t)((kt + 1) * 64 + s * 16 + l16) * D_MODEL + h * HD;
                kn0[s] = *(const short8*)&kb[koff + 8 * g4];
                kn1[s] = *(const short8*)&kb[koff + 32 + 8 * g4];
            }
            const size_t voff = (size_t)((kt + 1) * 64 + lane) * D_MODEL + h * HD + w * 16;
            vn0 = *(const ushort8*)&vb[voff];
            vn1 = *(const ushort8*)&vb[voff + 8];
        }

        __syncthreads();   // Vt[cur] staged (also fences prev-iter reads)

        // ---- S^T = K Q^T : sf[s][r] = S[key=s*16+g4*4+r][q=l16] ----
        f32x4 sf[4];
#pragma unroll
        for (int s = 0; s < 4; ++s) {
            f32x4 t = (f32x4){0.0f, 0.0f, 0.0f, 0.0f};
            t = __builtin_amdgcn_mfma_f32_16x16x32_bf16(ka0[s], q0, t, 0, 0, 0);
            t = __builtin_amdgcn_mfma_f32_16x16x32_bf16(ka1[s], q1, t, 0, 0, 0);
            sf[s] = t;
        }

        float mt = -INFINITY;
        if (kt == qt) {
            const int ql = w * 16 + l16;
#pragma unroll
            for (int s = 0; s < 4; ++s)
#pragma unroll
                for (int r = 0; r < 4; ++r) {
                    const float sc = sf[s][r] * 0.125f;
                    sf[s][r] = (s * 16 + g4 * 4 + r > ql) ? -INFINITY : sc;
                    mt = fmaxf(mt, sf[s][r]);
                }
        } else {
#pragma unroll
            for (int s = 0; s < 4; ++s)
#pragma unroll
                for (int r = 0; r < 4; ++r) {
                    sf[s][r] *= 0.125f;
                    mt = fmaxf(mt, sf[s][r]);
                }
        }
        mt = fmaxf(mt, __shfl_xor(mt, 16, 64));
        mt = fmaxf(mt, __shfl_xor(mt, 32, 64));

        const float mnew = fmaxf(m, mt);
        const float corr = __expf(m - mnew);
        m = mnew;

        float ps = 0.0f;
#pragma unroll
        for (int s = 0; s < 4; ++s) {
            const float e0 = __expf(sf[s][0] - m);
            const float e1 = __expf(sf[s][1] - m);
            const float e2 = __expf(sf[s][2] - m);
            const float e3 = __expf(sf[s][3] - m);
            ps += (e0 + e1) + (e2 + e3);
            uint2 pk;
            pk.x = cvt_pk_bf16(e0, e1);
            pk.y = cvt_pk_bf16(e2, e3);
            *(uint2*)&Pl[w][l16][s * 16 + g4 * 4] = pk;
        }
        ps += __shfl_xor(ps, 16, 64);
        ps += __shfl_xor(ps, 32, 64);
        lsum = lsum * corr + ps;

        float corrq[4];
#pragma unroll
        for (int r = 0; r < 4; ++r) corrq[r] = __shfl(corr, g4 * 4 + r, 64);
#pragma unroll
        for (int d = 0; d < 4; ++d)
#pragma unroll
            for (int r = 0; r < 4; ++r) acc[d][r] *= corrq[r];

        // ---- PV ----
        const short8 pa0 = *(const short8*)&Pl[w][l16][8 * g4];
        const short8 pa1 = *(const short8*)&Pl[w][l16][32 + 8 * g4];
#pragma unroll
        for (int d = 0; d < 4; ++d) {
            const short8 v0 = *(const short8*)&Vt[cur][d * 16 + l16][8 * g4];
            const short8 v1 = *(const short8*)&Vt[cur][d * 16 + l16][32 + 8 * g4];
            acc[d] = __builtin_amdgcn_mfma_f32_16x16x32_bf16(pa0, v0, acc[d], 0, 0, 0);
            acc[d] = __builtin_amdgcn_mfma_f32_16x16x32_bf16(pa1, v1, acc[d], 0, 0, 0);
        }

        if (kt + 1 < kt1) {
#pragma unroll
            for (int s = 0; s < 4; ++s) { ka0[s] = kn0[s]; ka1[s] = kn1[s]; }
            va0 = vn0; va1 = vn1;
        }
    }

    if (mode == 0) {
        const float lse = m + __logf(lsum);
        const float scale = 1.0f / (1.0f + __expf(-(lse - sink[h])));
        const float fv = scale / lsum;
        float fq[4];
#pragma unroll
        for (int r = 0; r < 4; ++r) fq[r] = __shfl(fv, g4 * 4 + r, 64);
#pragma unroll
        for (int r = 0; r < 4; ++r) {
            const size_t yoff = (size_t)(qt * 64 + w * 16 + g4 * 4 + r) * D_MODEL + h * HD + l16;
#pragma unroll
            for (int d = 0; d < 4; ++d)
                yb[yoff + d * 16] = f2bf(acc[d][r] * fq[r]);
        }
    } else {
        const int pi = ((qt - 16) * 16 + h) * 2 + (mode - 1);
        if (g4 == 0) {
            float* ml = part_ml + (size_t)pi * 128;
            ml[w * 16 + l16]      = m;
            ml[64 + w * 16 + l16] = lsum;
        }
        float* pa = part_acc + (size_t)pi * 4096;
#pragma unroll
        for (int r = 0; r < 4; ++r) {
            const int row = w * 16 + g4 * 4 + r;
#pragma unroll
            for (int d = 0; d < 4; ++d)
                pa[row * 64 + d * 16 + l16] = acc[d][r];
        }
    }
}

// ---------------------------------------------------------------------------
// Merge the two key-half partials for qt>=16 and apply sink scaling.
// Block = one (qt,h) unit; thread t handles row t>>2, cols (t&3)*16..+15.
// ---------------------------------------------------------------------------
__global__ __launch_bounds__(256) void attn_combine(const float* __restrict__ part_acc,
                                                    const float* __restrict__ part_ml,
                                                    const float* __restrict__ sink,
                                                    ushort_t* __restrict__ yb) {
    const int si = blockIdx.x;          // (qt-16)*16 + h
    const int h  = si & 15;
    const int qt = 16 + (si >> 4);
    const int t  = threadIdx.x;
    const int row = t >> 2;
    const int c0  = (t & 3) * 16;

    const float* a0 = part_acc + ((size_t)si * 2) * 4096 + row * 64 + c0;
    const float* a1 = a0 + 4096;
    const float* ml = part_ml + (size_t)si * 2 * 128;
    const float m0 = ml[row],       l0 = ml[64 + row];
    const float m1 = ml[128 + row], l1 = ml[192 + row];
    const float M  = fmaxf(m0, m1);
    const float e0 = __expf(m0 - M), e1 = __expf(m1 - M);
    const float l  = l0 * e0 + l1 * e1;
    const float lse = M + __logf(l);
    const float scale = 1.0f / (1.0f + __expf(-(lse - sink[h])));
    const float f = scale / l;

    ushort8 o[2];
#pragma unroll
    for (int j = 0; j < 16; ++j) {
        const float v = (a0[j] * e0 + a1[j] * e1) * f;
        o[j >> 3][j & 7] = f2bf(v);
    }
    ushort_t* yp = yb + (size_t)(qt * 64 + row) * D_MODEL + h * HD + c0;
    *(ushort8*)yp       = o[0];
    *(ushort8*)(yp + 8) = o[1];
}

// ---------------------------------------------------------------------------
extern "C" void kernel_launch(void* const* d_in, const int* in_sizes, int n_in,
                              void* d_out, int out_size, void* d_ws, size_t ws_size,
                              hipStream_t stream) {
    const float* x    = (const float*)d_in[0];
    const float* vi   = (const float*)d_in[1];
    const float* Wq   = (const float*)d_in[2];
    const float* Wk   = (const float*)d_in[3];
    const float* Wv   = (const float*)d_in[4];
    const float* Wo   = (const float*)d_in[5];
    const float* lamb = (const float*)d_in[6];
    const float* sink = (const float*)d_in[7];
    float* out = (float*)d_out;

    const size_t TD = (size_t)T_SEQ * D_MODEL;    // 2M elts
    const size_t WD = (size_t)D_MODEL * D_MODEL;  // 1M elts
    ushort_t* qbuf = (ushort_t*)d_ws;             // [ 0, 4)MB
    ushort_t* kbuf = qbuf + TD;                   // [ 4, 8)MB
    ushort_t* vbuf = kbuf + TD;                   // [ 8,12)MB
    ushort_t* yb   = vbuf + TD;                   // [12,16)MB
    ushort_t* wob  = yb + TD;                     // [16,18)MB
    ushort_t* xb   = wob + WD;                    // [18,22)MB
    ushort_t* wqb  = xb + TD;                     // [22,24)MB
    ushort_t* wkb  = wqb + WD;                    // [24,26)MB
    ushort_t* wvb  = wkb + WD;                    // [26,28)MB
    // attn partials overlay the staging buffers (dead after the QKV GEMM):
    float* part_acc = (float*)xb;                 // 8 MB  [18,26)MB
    float* part_ml  = (float*)wvb;                // 256 KB in [26,28)MB

    cast_to_bf16<<<dim3(512, 6), 256, 0, stream>>>(x, Wq, Wk, Wv, Wo,
                                                   xb, wqb, wkb, wvb, wob);

    gemm_bf16_nt<true><<<dim3(D_MODEL / 128, T_SEQ / 128, 3), 256, 0, stream>>>(
        xb, wqb, wkb, wvb, qbuf, kbuf, vbuf, T_SEQ, D_MODEL, D_MODEL);

    norm_rope<<<dim3(T_SEQ, NH / 4), 256, 0, stream>>>(qbuf, kbuf, vbuf, vi, lamb);

    attn_mfma<<<dim3(768), 256, 0, stream>>>(qbuf, kbuf, vbuf, sink, yb,
                                             part_acc, part_ml);
    attn_combine<<<dim3(256), 256, 0, stream>>>(part_acc, part_ml, sink, yb);

    gemm_bf16_nt<false><<<dim3(D_MODEL / 128, T_SEQ / 128, 1), 256, 0, stream>>>(
        yb, wob, wob, wob, out, out, out, T_SEQ, D_MODEL, D_MODEL);
}

// Round 9
// 125.752 us; speedup vs baseline: 1.0036x; 1.0036x over previous
//
#include <hip/hip_runtime.h>
#include <math.h>

#define T_SEQ 2048
#define D_MODEL 1024
#define NH 16
#define HD 64
#define RMS_EPS 1.1920928955078125e-07f

typedef unsigned short ushort_t;
typedef __attribute__((ext_vector_type(8))) short short8;
typedef __attribute__((ext_vector_type(8))) unsigned short ushort8;
typedef __attribute__((ext_vector_type(4))) float f32x4;

static __device__ __forceinline__ unsigned short f2bf(float f) {
    union { float f; unsigned u; } v; v.f = f;
    unsigned r = v.u + 0x7fff + ((v.u >> 16) & 1);   // RNE
    return (unsigned short)(r >> 16);
}
static __device__ __forceinline__ float bf2f(unsigned short b) {
    union { unsigned u; float f; } v; v.u = ((unsigned)b) << 16;
    return v.f;
}
static __device__ __forceinline__ unsigned cvt_pk_bf16(float lo, float hi) {
    unsigned r;
    asm("v_cvt_pk_bf16_f32 %0, %1, %2" : "=v"(r) : "v"(lo), "v"(hi));
    return r;
}
static __device__ __forceinline__ void gl_lds16(const ushort_t* g, ushort_t* l) {
    __builtin_amdgcn_global_load_lds(
        (const __attribute__((address_space(1))) unsigned int*)g,
        (__attribute__((address_space(3))) unsigned int*)l, 16, 0, 0);
}

// ---------------------------------------------------------------------------
// Cast f32 -> bf16: x (2M elements, segs 0-1) and the 4 weights (1M each).
// ---------------------------------------------------------------------------
__global__ __launch_bounds__(256) void cast_to_bf16(
    const float* __restrict__ x, const float* __restrict__ wq,
    const float* __restrict__ wk, const float* __restrict__ wv,
    const float* __restrict__ wo,
    ushort_t* __restrict__ xb, ushort_t* __restrict__ wqb,
    ushort_t* __restrict__ wkb, ushort_t* __restrict__ wvb,
    ushort_t* __restrict__ wob) {
    const int seg = blockIdx.y;
    const float* src; ushort_t* dst; size_t base = 0;
    if (seg == 0)      { src = x;  dst = xb; }
    else if (seg == 1) { src = x;  dst = xb; base = 1u << 20; }
    else if (seg == 2) { src = wq; dst = wqb; }
    else if (seg == 3) { src = wk; dst = wkb; }
    else if (seg == 4) { src = wv; dst = wvb; }
    else               { src = wo; dst = wob; }
    const size_t i = base + ((size_t)blockIdx.x * 256 + threadIdx.x) * 8;
    float4 a = *(const float4*)&src[i];
    float4 b = *(const float4*)&src[i + 4];
    ushort8 o;
    o[0] = f2bf(a.x); o[1] = f2bf(a.y); o[2] = f2bf(a.z); o[3] = f2bf(a.w);
    o[4] = f2bf(b.x); o[5] = f2bf(b.y); o[6] = f2bf(b.z); o[7] = f2bf(b.w);
    *(ushort8*)&dst[i] = o;
}

// ---------------------------------------------------------------------------
// bf16 MFMA GEMM (unchanged): C[M,N] = A[M,K] @ B[N,K]^T.
// ---------------------------------------------------------------------------
template<bool BF16OUT>
__global__ __launch_bounds__(256) void gemm_bf16_nt(
    const ushort_t* __restrict__ A,
    const ushort_t* __restrict__ B0, const ushort_t* __restrict__ B1,
    const ushort_t* __restrict__ B2,
    void* __restrict__ C0, void* __restrict__ C1, void* __restrict__ C2,
    int M, int N, int K) {
    __shared__ ushort_t As[128 * 64];
    __shared__ ushort_t Bs[128 * 64];

    const int z = blockIdx.z;
    const ushort_t* B = (z == 0) ? B0 : (z == 1) ? B1 : B2;
    void* Cv          = (z == 0) ? C0 : (z == 1) ? C1 : C2;

    const int tid = threadIdx.x;
    const int w = tid >> 6;
    const int l = tid & 63;
    const int wr = w >> 1, wc = w & 1;
    const int l16 = l & 15, g4 = l >> 4;
    const int row0 = blockIdx.y * 128;
    const int col0 = blockIdx.x * 128;

    const int srow = tid >> 3;
    const int scol = (tid & 7) * 8;
    const ushort_t* ga = A + (size_t)(row0 + srow) * K + scol;
    const ushort_t* gb = B + (size_t)(col0 + srow) * K + scol;
    ushort_t* lA = &As[w * 512];
    ushort_t* lB = &Bs[w * 512];

    f32x4 acc[4][4];
#pragma unroll
    for (int m = 0; m < 4; ++m)
#pragma unroll
        for (int n = 0; n < 4; ++n)
            acc[m][n] = (f32x4){0.0f, 0.0f, 0.0f, 0.0f};

    for (int k0 = 0; k0 < K; k0 += 64) {
        __syncthreads();
#pragma unroll
        for (int i = 0; i < 4; ++i) {
            gl_lds16(ga + (size_t)i * 32 * K + k0, lA + i * 2048);
            gl_lds16(gb + (size_t)i * 32 * K + k0, lB + i * 2048);
        }
        __syncthreads();
#pragma unroll
        for (int kk = 0; kk < 2; ++kk) {
            short8 af[4], bfr[4];
#pragma unroll
            for (int m = 0; m < 4; ++m)
                af[m] = *(const short8*)&As[(wr * 64 + m * 16 + l16) * 64 + kk * 32 + g4 * 8];
#pragma unroll
            for (int n = 0; n < 4; ++n)
                bfr[n] = *(const short8*)&Bs[(wc * 64 + n * 16 + l16) * 64 + kk * 32 + g4 * 8];
#pragma unroll
            for (int m = 0; m < 4; ++m)
#pragma unroll
                for (int n = 0; n < 4; ++n)
                    acc[m][n] = __builtin_amdgcn_mfma_f32_16x16x32_bf16(af[m], bfr[n], acc[m][n], 0, 0, 0);
        }
    }

#pragma unroll
    for (int m = 0; m < 4; ++m) {
        const int grow = row0 + wr * 64 + m * 16 + g4 * 4;
#pragma unroll
        for (int n = 0; n < 4; ++n) {
            const int gcol = col0 + wc * 64 + n * 16 + l16;
#pragma unroll
            for (int r = 0; r < 4; ++r) {
                if (BF16OUT)
                    ((ushort_t*)Cv)[(size_t)(grow + r) * N + gcol] = f2bf(acc[m][n][r]);
                else
                    ((float*)Cv)[(size_t)(grow + r) * N + gcol] = acc[m][n][r];
            }
        }
    }
}

// ---------------------------------------------------------------------------
// In-place on bf16 q,k,v: v-blend, rmsnorm, rope (unchanged).
// ---------------------------------------------------------------------------
__global__ __launch_bounds__(256) void norm_rope(ushort_t* __restrict__ qb,
                                                 ushort_t* __restrict__ kb,
                                                 ushort_t* __restrict__ vb,
                                                 const float* __restrict__ vi,
                                                 const float* __restrict__ lamb) {
    const int w = threadIdx.x >> 6;
    const int lane = threadIdx.x & 63;
    const int t = blockIdx.x;
    const int h = blockIdx.y * 4 + w;
    const size_t idx = (size_t)t * D_MODEL + h * HD + lane;

    const float lam = lamb[0];
    float qv = bf2f(qb[idx]);
    float kv = bf2f(kb[idx]);
    float vv = (1.0f - lam) * bf2f(vb[idx]) + lam * vi[idx];
    vb[idx] = f2bf(vv);

    float sq = qv * qv;
    float sk = kv * kv;
#pragma unroll
    for (int m = 1; m <= 32; m <<= 1) {
        sq += __shfl_xor(sq, m, 64);
        sk += __shfl_xor(sk, m, 64);
    }
    const float rq = rsqrtf(sq * (1.0f / 64.0f) + RMS_EPS);
    const float rk = rsqrtf(sk * (1.0f / 64.0f) + RMS_EPS);
    float qn = qv * rq;
    float kn = kv * rk;

    const int i = lane & 31;
    const float inv = exp2f(-0.4152410118609203f * (float)i);
    const float ang = (float)t * inv;
    float c, s;
    sincosf(ang, &s, &c);
    float qp = __shfl_xor(qn, 32, 64);
    float kp = __shfl_xor(kn, 32, 64);
    float qo, ko;
    if (lane < 32) {
        qo = qn * c + qp * s;
        ko = kn * c + kp * s;
    } else {
        qo = qn * c - qp * s;
        ko = kn * c - kp * s;
    }
    qb[idx] = f2bf(qo);
    kb[idx] = f2bf(ko);
}

// ---------------------------------------------------------------------------
// Flash attention v4: SAME structure as v3 (split-K, swapped QK^T, dbuf V,
// cvt_pk P-stores) with ONE fix: the per-iter barrier moved BEFORE the
// prefetch issue. v3 had stage -> prefetch -> barrier; the barrier's implicit
// s_waitcnt vmcnt(0) made every iteration wait for the "prefetch" loads,
// serializing full memory latency into the chain. Now: stage -> barrier ->
// prefetch -> compute, so loads overlap the whole compute phase.
// ---------------------------------------------------------------------------
__global__ __launch_bounds__(256) void attn_mfma(const ushort_t* __restrict__ qb,
                                                 const ushort_t* __restrict__ kb,
                                                 const ushort_t* __restrict__ vb,
                                                 const float* __restrict__ sink,
                                                 ushort_t* __restrict__ yb,
                                                 float* __restrict__ part_acc,
                                                 float* __restrict__ part_ml) {
    const int b = blockIdx.x;
    int h, qt, kt0, kt1, mode;   // mode 0 = full->y, 1/2 = partial half 0/1
    if (b < 512) {
        qt = 31 - (b >> 5);
        const int rem = b & 31;
        h = rem >> 1;
        const int half = rem & 1;
        const int mid = (qt + 1) >> 1;
        kt0 = half ? mid : 0;
        kt1 = half ? (qt + 1) : mid;
        mode = 1 + half;
    } else {
        const int rem = b - 512;
        qt = 15 - (rem >> 4);
        h = rem & 15;
        kt0 = 0; kt1 = qt + 1; mode = 0;
    }

    __shared__ ushort_t Vt[2][64][72];      // V transposed, double-buffered
    __shared__ ushort_t Pl[4][16][72];      // per-wave P (wave-local)

    const int tid  = threadIdx.x;
    const int w    = tid >> 6;
    const int lane = tid & 63;
    const int l16  = lane & 15;
    const int g4   = lane >> 4;

    // Q B-frags (persist): B[k=d][col=q=l16]
    const size_t qoff = (size_t)(qt * 64 + w * 16 + l16) * D_MODEL + h * HD;
    const short8 q0 = *(const short8*)&qb[qoff + 8 * g4];
    const short8 q1 = *(const short8*)&qb[qoff + 32 + 8 * g4];

    // current K A-frags + V staging regs (tile kt0)
    short8 ka0[4], ka1[4];
    ushort8 va0, va1;
#pragma unroll
    for (int s = 0; s < 4; ++s) {
        const size_t koff = (size_t)(kt0 * 64 + s * 16 + l16) * D_MODEL + h * HD;
        ka0[s] = *(const short8*)&kb[koff + 8 * g4];
        ka1[s] = *(const short8*)&kb[koff + 32 + 8 * g4];
    }
    {
        const size_t voff = (size_t)(kt0 * 64 + lane) * D_MODEL + h * HD + w * 16;
        va0 = *(const ushort8*)&vb[voff];
        va1 = *(const ushort8*)&vb[voff + 8];
    }

    float m = -INFINITY, lsum = 0.0f;
    f32x4 acc[4];
#pragma unroll
    for (int d = 0; d < 4; ++d) acc[d] = (f32x4){0.0f, 0.0f, 0.0f, 0.0f};

    for (int kt = kt0; kt < kt1; ++kt) {
        const int cur = kt & 1;

        // stage current V regs -> Vt[cur]
#pragma unroll
        for (int j = 0; j < 8; ++j) {
            Vt[cur][w * 16 + j][lane]     = va0[j];
            Vt[cur][w * 16 + 8 + j][lane] = va1[j];
        }

        __syncthreads();   // orders Vt[cur] writes; prior-iter loads already consumed

        // prefetch next tile K/V into regs — now AFTER the barrier, so these
        // loads overlap the entire QK/softmax/PV phase below.
        short8 kn0[4], kn1[4];
        ushort8 vn0, vn1;
        if (kt + 1 < kt1) {
#pragma unroll
            for (int s = 0; s < 4; ++s) {
                const size_t koff = (size_t)((kt + 1) * 64 + s * 16 + l16) * D_MODEL + h * HD;
                kn0[s] = *(const short8*)&kb[koff + 8 * g4];
                kn1[s] = *(const short8*)&kb[koff + 32 + 8 * g4];
            }
            const size_t voff = (size_t)((kt + 1) * 64 + lane) * D_MODEL + h * HD + w * 16;
            vn0 = *(const ushort8*)&vb[voff];
            vn1 = *(const ushort8*)&vb[voff + 8];
        }

        // ---- S^T = K Q^T : sf[s][r] = S[key=s*16+g4*4+r][q=l16] ----
        f32x4 sf[4];
#pragma unroll
        for (int s = 0; s < 4; ++s) {
            f32x4 t = (f32x4){0.0f, 0.0f, 0.0f, 0.0f};
            t = __builtin_amdgcn_mfma_f32_16x16x32_bf16(ka0[s], q0, t, 0, 0, 0);
            t = __builtin_amdgcn_mfma_f32_16x16x32_bf16(ka1[s], q1, t, 0, 0, 0);
            sf[s] = t;
        }

        float mt = -INFINITY;
        if (kt == qt) {
            const int ql = w * 16 + l16;
#pragma unroll
            for (int s = 0; s < 4; ++s)
#pragma unroll
                for (int r = 0; r < 4; ++r) {
                    const float sc = sf[s][r] * 0.125f;
                    sf[s][r] = (s * 16 + g4 * 4 + r > ql) ? -INFINITY : sc;
                    mt = fmaxf(mt, sf[s][r]);
                }
        } else {
#pragma unroll
            for (int s = 0; s < 4; ++s)
#pragma unroll
                for (int r = 0; r < 4; ++r) {
                    sf[s][r] *= 0.125f;
                    mt = fmaxf(mt, sf[s][r]);
                }
        }
        mt = fmaxf(mt, __shfl_xor(mt, 16, 64));
        mt = fmaxf(mt, __shfl_xor(mt, 32, 64));

        const float mnew = fmaxf(m, mt);
        const float corr = __expf(m - mnew);
        m = mnew;

        float ps = 0.0f;
#pragma unroll
        for (int s = 0; s < 4; ++s) {
            const float e0 = __expf(sf[s][0] - m);
            const float e1 = __expf(sf[s][1] - m);
            const float e2 = __expf(sf[s][2] - m);
            const float e3 = __expf(sf[s][3] - m);
            ps += (e0 + e1) + (e2 + e3);
            uint2 pk;
            pk.x = cvt_pk_bf16(e0, e1);
            pk.y = cvt_pk_bf16(e2, e3);
            *(uint2*)&Pl[w][l16][s * 16 + g4 * 4] = pk;
        }
        ps += __shfl_xor(ps, 16, 64);
        ps += __shfl_xor(ps, 32, 64);
        lsum = lsum * corr + ps;

        float corrq[4];
#pragma unroll
        for (int r = 0; r < 4; ++r) corrq[r] = __shfl(corr, g4 * 4 + r, 64);
#pragma unroll
        for (int d = 0; d < 4; ++d)
#pragma unroll
            for (int r = 0; r < 4; ++r) acc[d][r] *= corrq[r];

        // ---- PV ----
        const short8 pa0 = *(const short8*)&Pl[w][l16][8 * g4];
        const short8 pa1 = *(const short8*)&Pl[w][l16][32 + 8 * g4];
#pragma unroll
        for (int d = 0; d < 4; ++d) {
            const short8 v0 = *(const short8*)&Vt[cur][d * 16 + l16][8 * g4];
            const short8 v1 = *(const short8*)&Vt[cur][d * 16 + l16][32 + 8 * g4];
            acc[d] = __builtin_amdgcn_mfma_f32_16x16x32_bf16(pa0, v0, acc[d], 0, 0, 0);
            acc[d] = __builtin_amdgcn_mfma_f32_16x16x32_bf16(pa1, v1, acc[d], 0, 0, 0);
        }

        if (kt + 1 < kt1) {
#pragma unroll
            for (int s = 0; s < 4; ++s) { ka0[s] = kn0[s]; ka1[s] = kn1[s]; }
            va0 = vn0; va1 = vn1;
        }
    }

    if (mode == 0) {
        const float lse = m + __logf(lsum);
        const float scale = 1.0f / (1.0f + __expf(-(lse - sink[h])));
        const float fv = scale / lsum;
        float fq[4];
#pragma unroll
        for (int r = 0; r < 4; ++r) fq[r] = __shfl(fv, g4 * 4 + r, 64);
#pragma unroll
        for (int r = 0; r < 4; ++r) {
            const size_t yoff = (size_t)(qt * 64 + w * 16 + g4 * 4 + r) * D_MODEL + h * HD + l16;
#pragma unroll
            for (int d = 0; d < 4; ++d)
                yb[yoff + d * 16] = f2bf(acc[d][r] * fq[r]);
        }
    } else {
        const int pi = ((qt - 16) * 16 + h) * 2 + (mode - 1);
        if (g4 == 0) {
            float* ml = part_ml + (size_t)pi * 128;
            ml[w * 16 + l16]      = m;
            ml[64 + w * 16 + l16] = lsum;
        }
        float* pa = part_acc + (size_t)pi * 4096;
#pragma unroll
        for (int r = 0; r < 4; ++r) {
            const int row = w * 16 + g4 * 4 + r;
#pragma unroll
            for (int d = 0; d < 4; ++d)
                pa[row * 64 + d * 16 + l16] = acc[d][r];
        }
    }
}

// ---------------------------------------------------------------------------
// Merge the two key-half partials for qt>=16 and apply sink scaling.
// ---------------------------------------------------------------------------
__global__ __launch_bounds__(256) void attn_combine(const float* __restrict__ part_acc,
                                                    const float* __restrict__ part_ml,
                                                    const float* __restrict__ sink,
                                                    ushort_t* __restrict__ yb) {
    const int si = blockIdx.x;          // (qt-16)*16 + h
    const int h  = si & 15;
    const int qt = 16 + (si >> 4);
    const int t  = threadIdx.x;
    const int row = t >> 2;
    const int c0  = (t & 3) * 16;

    const float* a0 = part_acc + ((size_t)si * 2) * 4096 + row * 64 + c0;
    const float* a1 = a0 + 4096;
    const float* ml = part_ml + (size_t)si * 2 * 128;
    const float m0 = ml[row],       l0 = ml[64 + row];
    const float m1 = ml[128 + row], l1 = ml[192 + row];
    const float M  = fmaxf(m0, m1);
    const float e0 = __expf(m0 - M), e1 = __expf(m1 - M);
    const float l  = l0 * e0 + l1 * e1;
    const float lse = M + __logf(l);
    const float scale = 1.0f / (1.0f + __expf(-(lse - sink[h])));
    const float f = scale / l;

    ushort8 o[2];
#pragma unroll
    for (int j = 0; j < 16; ++j) {
        const float v = (a0[j] * e0 + a1[j] * e1) * f;
        o[j >> 3][j & 7] = f2bf(v);
    }
    ushort_t* yp = yb + (size_t)(qt * 64 + row) * D_MODEL + h * HD + c0;
    *(ushort8*)yp       = o[0];
    *(ushort8*)(yp + 8) = o[1];
}

// ---------------------------------------------------------------------------
extern "C" void kernel_launch(void* const* d_in, const int* in_sizes, int n_in,
                              void* d_out, int out_size, void* d_ws, size_t ws_size,
                              hipStream_t stream) {
    const float* x    = (const float*)d_in[0];
    const float* vi   = (const float*)d_in[1];
    const float* Wq   = (const float*)d_in[2];
    const float* Wk   = (const float*)d_in[3];
    const float* Wv   = (const float*)d_in[4];
    const float* Wo   = (const float*)d_in[5];
    const float* lamb = (const float*)d_in[6];
    const float* sink = (const float*)d_in[7];
    float* out = (float*)d_out;

    const size_t TD = (size_t)T_SEQ * D_MODEL;    // 2M elts
    const size_t WD = (size_t)D_MODEL * D_MODEL;  // 1M elts
    ushort_t* qbuf = (ushort_t*)d_ws;             // [ 0, 4)MB
    ushort_t* kbuf = qbuf + TD;                   // [ 4, 8)MB
    ushort_t* vbuf = kbuf + TD;                   // [ 8,12)MB
    ushort_t* yb   = vbuf + TD;                   // [12,16)MB
    ushort_t* wob  = yb + TD;                     // [16,18)MB
    ushort_t* xb   = wob + WD;                    // [18,22)MB
    ushort_t* wqb  = xb + TD;                     // [22,24)MB
    ushort_t* wkb  = wqb + WD;                    // [24,26)MB
    ushort_t* wvb  = wkb + WD;                    // [26,28)MB
    // attn partials overlay the staging buffers (dead after the QKV GEMM):
    float* part_acc = (float*)xb;                 // 8 MB  [18,26)MB
    float* part_ml  = (float*)wvb;                // 256 KB in [26,28)MB

    cast_to_bf16<<<dim3(512, 6), 256, 0, stream>>>(x, Wq, Wk, Wv, Wo,
                                                   xb, wqb, wkb, wvb, wob);

    gemm_bf16_nt<true><<<dim3(D_MODEL / 128, T_SEQ / 128, 3), 256, 0, stream>>>(
        xb, wqb, wkb, wvb, qbuf, kbuf, vbuf, T_SEQ, D_MODEL, D_MODEL);

    norm_rope<<<dim3(T_SEQ, NH / 4), 256, 0, stream>>>(qbuf, kbuf, vbuf, vi, lamb);

    attn_mfma<<<dim3(768), 256, 0, stream>>>(qbuf, kbuf, vbuf, sink, yb,
                                             part_acc, part_ml);
    attn_combine<<<dim3(256), 256, 0, stream>>>(part_acc, part_ml, sink, yb);

    gemm_bf16_nt<false><<<dim3(D_MODEL / 128, T_SEQ / 128, 1), 256, 0, stream>>>(
        yb, wob, wob, wob, out, out, out, T_SEQ, D_MODEL, D_MODEL);
}

// Round 10
// 104.263 us; speedup vs baseline: 1.2104x; 1.2061x over previous
//
#include <hip/hip_runtime.h>
#include <math.h>

#define T_SEQ 2048
#define D_MODEL 1024
#define NH 16
#define HD 64
#define RMS_EPS 1.1920928955078125e-07f

typedef unsigned short ushort_t;
typedef __attribute__((ext_vector_type(8))) short short8;
typedef __attribute__((ext_vector_type(8))) unsigned short ushort8;
typedef __attribute__((ext_vector_type(4))) float f32x4;

static __device__ __forceinline__ unsigned short f2bf(float f) {
    union { float f; unsigned u; } v; v.f = f;
    unsigned r = v.u + 0x7fff + ((v.u >> 16) & 1);   // RNE
    return (unsigned short)(r >> 16);
}
static __device__ __forceinline__ float bf2f(unsigned short b) {
    union { unsigned u; float f; } v; v.u = ((unsigned)b) << 16;
    return v.f;
}
static __device__ __forceinline__ unsigned cvt_pk_bf16(float lo, float hi) {
    unsigned r;
    asm("v_cvt_pk_bf16_f32 %0, %1, %2" : "=v"(r) : "v"(lo), "v"(hi));
    return r;
}
static __device__ __forceinline__ void gl_lds16(const ushort_t* g, ushort_t* l) {
    __builtin_amdgcn_global_load_lds(
        (const __attribute__((address_space(1))) unsigned int*)g,
        (__attribute__((address_space(3))) unsigned int*)l, 16, 0, 0);
}

// ---------------------------------------------------------------------------
// Cast f32 -> bf16: x (2M elements, segs 0-1) and the 4 weights (1M each).
// ---------------------------------------------------------------------------
__global__ __launch_bounds__(256) void cast_to_bf16(
    const float* __restrict__ x, const float* __restrict__ wq,
    const float* __restrict__ wk, const float* __restrict__ wv,
    const float* __restrict__ wo,
    ushort_t* __restrict__ xb, ushort_t* __restrict__ wqb,
    ushort_t* __restrict__ wkb, ushort_t* __restrict__ wvb,
    ushort_t* __restrict__ wob) {
    const int seg = blockIdx.y;
    const float* src; ushort_t* dst; size_t base = 0;
    if (seg == 0)      { src = x;  dst = xb; }
    else if (seg == 1) { src = x;  dst = xb; base = 1u << 20; }
    else if (seg == 2) { src = wq; dst = wqb; }
    else if (seg == 3) { src = wk; dst = wkb; }
    else if (seg == 4) { src = wv; dst = wvb; }
    else               { src = wo; dst = wob; }
    const size_t i = base + ((size_t)blockIdx.x * 256 + threadIdx.x) * 8;
    float4 a = *(const float4*)&src[i];
    float4 b = *(const float4*)&src[i + 4];
    ushort8 o;
    o[0] = f2bf(a.x); o[1] = f2bf(a.y); o[2] = f2bf(a.z); o[3] = f2bf(a.w);
    o[4] = f2bf(b.x); o[5] = f2bf(b.y); o[6] = f2bf(b.z); o[7] = f2bf(b.w);
    *(ushort8*)&dst[i] = o;
}

// ---------------------------------------------------------------------------
// bf16 MFMA GEMM (unchanged): C[M,N] = A[M,K] @ B[N,K]^T.
// ---------------------------------------------------------------------------
template<bool BF16OUT>
__global__ __launch_bounds__(256) void gemm_bf16_nt(
    const ushort_t* __restrict__ A,
    const ushort_t* __restrict__ B0, const ushort_t* __restrict__ B1,
    const ushort_t* __restrict__ B2,
    void* __restrict__ C0, void* __restrict__ C1, void* __restrict__ C2,
    int M, int N, int K) {
    __shared__ ushort_t As[128 * 64];
    __shared__ ushort_t Bs[128 * 64];

    const int z = blockIdx.z;
    const ushort_t* B = (z == 0) ? B0 : (z == 1) ? B1 : B2;
    void* Cv          = (z == 0) ? C0 : (z == 1) ? C1 : C2;

    const int tid = threadIdx.x;
    const int w = tid >> 6;
    const int l = tid & 63;
    const int wr = w >> 1, wc = w & 1;
    const int l16 = l & 15, g4 = l >> 4;
    const int row0 = blockIdx.y * 128;
    const int col0 = blockIdx.x * 128;

    const int srow = tid >> 3;
    const int scol = (tid & 7) * 8;
    const ushort_t* ga = A + (size_t)(row0 + srow) * K + scol;
    const ushort_t* gb = B + (size_t)(col0 + srow) * K + scol;
    ushort_t* lA = &As[w * 512];
    ushort_t* lB = &Bs[w * 512];

    f32x4 acc[4][4];
#pragma unroll
    for (int m = 0; m < 4; ++m)
#pragma unroll
        for (int n = 0; n < 4; ++n)
            acc[m][n] = (f32x4){0.0f, 0.0f, 0.0f, 0.0f};

    for (int k0 = 0; k0 < K; k0 += 64) {
        __syncthreads();
#pragma unroll
        for (int i = 0; i < 4; ++i) {
            gl_lds16(ga + (size_t)i * 32 * K + k0, lA + i * 2048);
            gl_lds16(gb + (size_t)i * 32 * K + k0, lB + i * 2048);
        }
        __syncthreads();
#pragma unroll
        for (int kk = 0; kk < 2; ++kk) {
            short8 af[4], bfr[4];
#pragma unroll
            for (int m = 0; m < 4; ++m)
                af[m] = *(const short8*)&As[(wr * 64 + m * 16 + l16) * 64 + kk * 32 + g4 * 8];
#pragma unroll
            for (int n = 0; n < 4; ++n)
                bfr[n] = *(const short8*)&Bs[(wc * 64 + n * 16 + l16) * 64 + kk * 32 + g4 * 8];
#pragma unroll
            for (int m = 0; m < 4; ++m)
#pragma unroll
                for (int n = 0; n < 4; ++n)
                    acc[m][n] = __builtin_amdgcn_mfma_f32_16x16x32_bf16(af[m], bfr[n], acc[m][n], 0, 0, 0);
        }
    }

#pragma unroll
    for (int m = 0; m < 4; ++m) {
        const int grow = row0 + wr * 64 + m * 16 + g4 * 4;
#pragma unroll
        for (int n = 0; n < 4; ++n) {
            const int gcol = col0 + wc * 64 + n * 16 + l16;
#pragma unroll
            for (int r = 0; r < 4; ++r) {
                if (BF16OUT)
                    ((ushort_t*)Cv)[(size_t)(grow + r) * N + gcol] = f2bf(acc[m][n][r]);
                else
                    ((float*)Cv)[(size_t)(grow + r) * N + gcol] = acc[m][n][r];
            }
        }
    }
}

// ---------------------------------------------------------------------------
// In-place on bf16 q,k,v: v-blend, rmsnorm, rope. NEW: kb is stored with a
// per-row 16B-chunk XOR swizzle (chunk c -> c ^ (t&7)) so attn's LDS tiles
// (filled linearly by global_load_lds) can be ds_read_b128 without the
// stride-128B bank degeneracy (T2, both-sides rule).
// ---------------------------------------------------------------------------
__global__ __launch_bounds__(256) void norm_rope(ushort_t* __restrict__ qb,
                                                 ushort_t* __restrict__ kb,
                                                 ushort_t* __restrict__ vb,
                                                 const float* __restrict__ vi,
                                                 const float* __restrict__ lamb) {
    const int w = threadIdx.x >> 6;
    const int lane = threadIdx.x & 63;
    const int t = blockIdx.x;
    const int h = blockIdx.y * 4 + w;
    const size_t idx = (size_t)t * D_MODEL + h * HD + lane;

    const float lam = lamb[0];
    float qv = bf2f(qb[idx]);
    float kv = bf2f(kb[idx]);
    float vv = (1.0f - lam) * bf2f(vb[idx]) + lam * vi[idx];
    vb[idx] = f2bf(vv);

    float sq = qv * qv;
    float sk = kv * kv;
#pragma unroll
    for (int m = 1; m <= 32; m <<= 1) {
        sq += __shfl_xor(sq, m, 64);
        sk += __shfl_xor(sk, m, 64);
    }
    const float rq = rsqrtf(sq * (1.0f / 64.0f) + RMS_EPS);
    const float rk = rsqrtf(sk * (1.0f / 64.0f) + RMS_EPS);
    float qn = qv * rq;
    float kn = kv * rk;

    const int i = lane & 31;
    const float inv = exp2f(-0.4152410118609203f * (float)i);
    const float ang = (float)t * inv;
    float c, s;
    sincosf(ang, &s, &c);
    float qp = __shfl_xor(qn, 32, 64);
    float kp = __shfl_xor(kn, 32, 64);
    float qo, ko;
    if (lane < 32) {
        qo = qn * c + qp * s;
        ko = kn * c + kp * s;
    } else {
        qo = qn * c - qp * s;
        ko = kn * c - kp * s;
    }
    qb[idx] = f2bf(qo);
    // swizzled K store: chunk (lane>>3) -> (lane>>3) ^ (t&7)
    const int kcol = ((((lane >> 3) ^ (t & 7)) << 3) | (lane & 7));
    kb[(size_t)t * D_MODEL + h * HD + kcol] = f2bf(ko);
}

// ---------------------------------------------------------------------------
// Flash attention v5: K tiles now staged via global_load_lds into
// double-buffered LDS (DMA cannot be sunk by the compiler -- r9 showed the
// register "prefetch" was compiled away, VGPR=76). K ds_reads use the XOR
// chunk swizzle matching norm_rope's pre-swizzled store. V keeps the
// register-prefetch path (2 loads/iter) with VGPR headroom from
// launch_bounds(256,2). Split-K + swapped QK^T + cvt_pk unchanged.
// ---------------------------------------------------------------------------
__global__ __launch_bounds__(256, 2) void attn_mfma(const ushort_t* __restrict__ qb,
                                                    const ushort_t* __restrict__ kb,
                                                    const ushort_t* __restrict__ vb,
                                                    const float* __restrict__ sink,
                                                    ushort_t* __restrict__ yb,
                                                    float* __restrict__ part_acc,
                                                    float* __restrict__ part_ml) {
    const int b = blockIdx.x;
    int h, qt, kt0, kt1, mode;   // mode 0 = full->y, 1/2 = partial half 0/1
    if (b < 512) {
        qt = 31 - (b >> 5);
        const int rem = b & 31;
        h = rem >> 1;
        const int half = rem & 1;
        const int mid = (qt + 1) >> 1;
        kt0 = half ? mid : 0;
        kt1 = half ? (qt + 1) : mid;
        mode = 1 + half;
    } else {
        const int rem = b - 512;
        qt = 15 - (rem >> 4);
        h = rem & 15;
        kt0 = 0; kt1 = qt + 1; mode = 0;
    }

    __shared__ ushort_t Kl[2][64 * 64];     // K tiles (swizzled rows), dbuf, 16 KB
    __shared__ ushort_t Vt[2][64][72];      // V transposed, dbuf, 18 KB
    __shared__ ushort_t Pl[4][16][72];      // per-wave P, 9 KB

    const int tid  = threadIdx.x;
    const int w    = tid >> 6;
    const int lane = tid & 63;
    const int l16  = lane & 15;
    const int g4   = lane >> 4;

    // Q B-frags (persist): B[k=d][col=q=l16]
    const size_t qoff = (size_t)(qt * 64 + w * 16 + l16) * D_MODEL + h * HD;
    const short8 q0 = *(const short8*)&qb[qoff + 8 * g4];
    const short8 q1 = *(const short8*)&qb[qoff + 32 + 8 * g4];

    // per-lane source offset pieces for the K DMA (wave w stages rows w*16..+15)
    const int krow_l = w * 16 + (lane >> 3);   // + i*8
    const int kcol_l = (lane & 7) * 8;

    // ---- prologue: DMA K tile kt0, load V tile kt0 into regs ----
#pragma unroll
    for (int i = 0; i < 2; ++i)
        gl_lds16(kb + ((size_t)(kt0 * 64 + krow_l + i * 8) << 10) + h * HD + kcol_l,
                 &Kl[kt0 & 1][w * 1024 + i * 512]);
    ushort8 va0, va1;
    {
        const size_t voff = (size_t)(kt0 * 64 + lane) * D_MODEL + h * HD + w * 16;
        va0 = *(const ushort8*)&vb[voff];
        va1 = *(const ushort8*)&vb[voff + 8];
    }

    float m = -INFINITY, lsum = 0.0f;
    f32x4 acc[4];
#pragma unroll
    for (int d = 0; d < 4; ++d) acc[d] = (f32x4){0.0f, 0.0f, 0.0f, 0.0f};

    for (int kt = kt0; kt < kt1; ++kt) {
        const int cur = kt & 1;

        // stage current V regs -> Vt[cur] (row uniform, lane-contiguous: conflict-free)
#pragma unroll
        for (int j = 0; j < 8; ++j) {
            Vt[cur][w * 16 + j][lane]     = va0[j];
            Vt[cur][w * 16 + 8 + j][lane] = va1[j];
        }

        __syncthreads();   // drains K DMA for [cur]; orders Vt[cur]; frees [cur^1]

        // prefetch next tile: K via DMA into Kl[cur^1], V into regs.
        ushort8 vn0, vn1;
        if (kt + 1 < kt1) {
#pragma unroll
            for (int i = 0; i < 2; ++i)
                gl_lds16(kb + ((size_t)((kt + 1) * 64 + krow_l + i * 8) << 10) + h * HD + kcol_l,
                         &Kl[cur ^ 1][w * 1024 + i * 512]);
            const size_t voff = (size_t)((kt + 1) * 64 + lane) * D_MODEL + h * HD + w * 16;
            vn0 = *(const ushort8*)&vb[voff];
            vn1 = *(const ushort8*)&vb[voff + 8];
        }

        // ---- K A-frags from LDS (swizzled), S^T = K Q^T ----
        f32x4 sf[4];
#pragma unroll
        for (int s = 0; s < 4; ++s) {
            const int row = s * 16 + l16;
            const int swz = l16 & 7;
            const short8 ka0 = *(const short8*)&Kl[cur][row * 64 + ((g4 ^ swz) << 3)];
            const short8 ka1 = *(const short8*)&Kl[cur][row * 64 + (((g4 + 4) ^ swz) << 3)];
            f32x4 t = (f32x4){0.0f, 0.0f, 0.0f, 0.0f};
            t = __builtin_amdgcn_mfma_f32_16x16x32_bf16(ka0, q0, t, 0, 0, 0);
            t = __builtin_amdgcn_mfma_f32_16x16x32_bf16(ka1, q1, t, 0, 0, 0);
            sf[s] = t;
        }

        float mt = -INFINITY;
        if (kt == qt) {
            const int ql = w * 16 + l16;
#pragma unroll
            for (int s = 0; s < 4; ++s)
#pragma unroll
                for (int r = 0; r < 4; ++r) {
                    const float sc = sf[s][r] * 0.125f;
                    sf[s][r] = (s * 16 + g4 * 4 + r > ql) ? -INFINITY : sc;
                    mt = fmaxf(mt, sf[s][r]);
                }
        } else {
#pragma unroll
            for (int s = 0; s < 4; ++s)
#pragma unroll
                for (int r = 0; r < 4; ++r) {
                    sf[s][r] *= 0.125f;
                    mt = fmaxf(mt, sf[s][r]);
                }
        }
        mt = fmaxf(mt, __shfl_xor(mt, 16, 64));
        mt = fmaxf(mt, __shfl_xor(mt, 32, 64));

        const float mnew = fmaxf(m, mt);
        const float corr = __expf(m - mnew);
        m = mnew;

        float ps = 0.0f;
#pragma unroll
        for (int s = 0; s < 4; ++s) {
            const float e0 = __expf(sf[s][0] - m);
            const float e1 = __expf(sf[s][1] - m);
            const float e2 = __expf(sf[s][2] - m);
            const float e3 = __expf(sf[s][3] - m);
            ps += (e0 + e1) + (e2 + e3);
            uint2 pk;
            pk.x = cvt_pk_bf16(e0, e1);
            pk.y = cvt_pk_bf16(e2, e3);
            *(uint2*)&Pl[w][l16][s * 16 + g4 * 4] = pk;
        }
        ps += __shfl_xor(ps, 16, 64);
        ps += __shfl_xor(ps, 32, 64);
        lsum = lsum * corr + ps;

        float corrq[4];
#pragma unroll
        for (int r = 0; r < 4; ++r) corrq[r] = __shfl(corr, g4 * 4 + r, 64);
#pragma unroll
        for (int d = 0; d < 4; ++d)
#pragma unroll
            for (int r = 0; r < 4; ++r) acc[d][r] *= corrq[r];

        // ---- PV ----
        const short8 pa0 = *(const short8*)&Pl[w][l16][8 * g4];
        const short8 pa1 = *(const short8*)&Pl[w][l16][32 + 8 * g4];
#pragma unroll
        for (int d = 0; d < 4; ++d) {
            const short8 v0 = *(const short8*)&Vt[cur][d * 16 + l16][8 * g4];
            const short8 v1 = *(const short8*)&Vt[cur][d * 16 + l16][32 + 8 * g4];
            acc[d] = __builtin_amdgcn_mfma_f32_16x16x32_bf16(pa0, v0, acc[d], 0, 0, 0);
            acc[d] = __builtin_amdgcn_mfma_f32_16x16x32_bf16(pa1, v1, acc[d], 0, 0, 0);
        }

        if (kt + 1 < kt1) { va0 = vn0; va1 = vn1; }
    }

    if (mode == 0) {
        const float lse = m + __logf(lsum);
        const float scale = 1.0f / (1.0f + __expf(-(lse - sink[h])));
        const float fv = scale / lsum;
        float fq[4];
#pragma unroll
        for (int r = 0; r < 4; ++r) fq[r] = __shfl(fv, g4 * 4 + r, 64);
#pragma unroll
        for (int r = 0; r < 4; ++r) {
            const size_t yoff = (size_t)(qt * 64 + w * 16 + g4 * 4 + r) * D_MODEL + h * HD + l16;
#pragma unroll
            for (int d = 0; d < 4; ++d)
                yb[yoff + d * 16] = f2bf(acc[d][r] * fq[r]);
        }
    } else {
        const int pi = ((qt - 16) * 16 + h) * 2 + (mode - 1);
        if (g4 == 0) {
            float* ml = part_ml + (size_t)pi * 128;
            ml[w * 16 + l16]      = m;
            ml[64 + w * 16 + l16] = lsum;
        }
        float* pa = part_acc + (size_t)pi * 4096;
#pragma unroll
        for (int r = 0; r < 4; ++r) {
            const int row = w * 16 + g4 * 4 + r;
#pragma unroll
            for (int d = 0; d < 4; ++d)
                pa[row * 64 + d * 16 + l16] = acc[d][r];
        }
    }
}

// ---------------------------------------------------------------------------
// Merge the two key-half partials for qt>=16 and apply sink scaling.
// ---------------------------------------------------------------------------
__global__ __launch_bounds__(256) void attn_combine(const float* __restrict__ part_acc,
                                                    const float* __restrict__ part_ml,
                                                    const float* __restrict__ sink,
                                                    ushort_t* __restrict__ yb) {
    const int si = blockIdx.x;          // (qt-16)*16 + h
    const int h  = si & 15;
    const int qt = 16 + (si >> 4);
    const int t  = threadIdx.x;
    const int row = t >> 2;
    const int c0  = (t & 3) * 16;

    const float* a0 = part_acc + ((size_t)si * 2) * 4096 + row * 64 + c0;
    const float* a1 = a0 + 4096;
    const float* ml = part_ml + (size_t)si * 2 * 128;
    const float m0 = ml[row],       l0 = ml[64 + row];
    const float m1 = ml[128 + row], l1 = ml[192 + row];
    const float M  = fmaxf(m0, m1);
    const float e0 = __expf(m0 - M), e1 = __expf(m1 - M);
    const float l  = l0 * e0 + l1 * e1;
    const float lse = M + __logf(l);
    const float scale = 1.0f / (1.0f + __expf(-(lse - sink[h])));
    const float f = scale / l;

    ushort8 o[2];
#pragma unroll
    for (int j = 0; j < 16; ++j) {
        const float v = (a0[j] * e0 + a1[j] * e1) * f;
        o[j >> 3][j & 7] = f2bf(v);
    }
    ushort_t* yp = yb + (size_t)(qt * 64 + row) * D_MODEL + h * HD + c0;
    *(ushort8*)yp       = o[0];
    *(ushort8*)(yp + 8) = o[1];
}

// ---------------------------------------------------------------------------
extern "C" void kernel_launch(void* const* d_in, const int* in_sizes, int n_in,
                              void* d_out, int out_size, void* d_ws, size_t ws_size,
                              hipStream_t stream) {
    const float* x    = (const float*)d_in[0];
    const float* vi   = (const float*)d_in[1];
    const float* Wq   = (const float*)d_in[2];
    const float* Wk   = (const float*)d_in[3];
    const float* Wv   = (const float*)d_in[4];
    const float* Wo   = (const float*)d_in[5];
    const float* lamb = (const float*)d_in[6];
    const float* sink = (const float*)d_in[7];
    float* out = (float*)d_out;

    const size_t TD = (size_t)T_SEQ * D_MODEL;    // 2M elts
    const size_t WD = (size_t)D_MODEL * D_MODEL;  // 1M elts
    ushort_t* qbuf = (ushort_t*)d_ws;             // [ 0, 4)MB
    ushort_t* kbuf = qbuf + TD;                   // [ 4, 8)MB
    ushort_t* vbuf = kbuf + TD;                   // [ 8,12)MB
    ushort_t* yb   = vbuf + TD;                   // [12,16)MB
    ushort_t* wob  = yb + TD;                     // [16,18)MB
    ushort_t* xb   = wob + WD;                    // [18,22)MB
    ushort_t* wqb  = xb + TD;                     // [22,24)MB
    ushort_t* wkb  = wqb + WD;                    // [24,26)MB
    ushort_t* wvb  = wkb + WD;                    // [26,28)MB
    // attn partials overlay the staging buffers (dead after the QKV GEMM):
    float* part_acc = (float*)xb;                 // 8 MB  [18,26)MB
    float* part_ml  = (float*)wvb;                // 256 KB in [26,28)MB

    cast_to_bf16<<<dim3(512, 6), 256, 0, stream>>>(x, Wq, Wk, Wv, Wo,
                                                   xb, wqb, wkb, wvb, wob);

    gemm_bf16_nt<true><<<dim3(D_MODEL / 128, T_SEQ / 128, 3), 256, 0, stream>>>(
        xb, wqb, wkb, wvb, qbuf, kbuf, vbuf, T_SEQ, D_MODEL, D_MODEL);

    norm_rope<<<dim3(T_SEQ, NH / 4), 256, 0, stream>>>(qbuf, kbuf, vbuf, vi, lamb);

    attn_mfma<<<dim3(768), 256, 0, stream>>>(qbuf, kbuf, vbuf, sink, yb,
                                             part_acc, part_ml);
    attn_combine<<<dim3(256), 256, 0, stream>>>(part_acc, part_ml, sink, yb);

    gemm_bf16_nt<false><<<dim3(D_MODEL / 128, T_SEQ / 128, 1), 256, 0, stream>>>(
        yb, wob, wob, wob, out, out, out, T_SEQ, D_MODEL, D_MODEL);
}